// Round 2
// baseline (58.522 us; speedup 1.0000x reference)
//
#include <hip/hip_runtime.h>
#include <hip/hip_bf16.h>

#define BATCH 8
#define SEQ   8192
#define DIM   512

// ---------------------------------------------------------------------------
// Workspace layout:
//   [0, SEG_BYTES)                : seg  (BATCH*SEQ int32)            256 KB
//   [SEG_BYTES, +PE_BYTES)        : pe   (SEQ positions x DIM f32)     16 MB
// ---------------------------------------------------------------------------
#define SEG_BYTES ((size_t)BATCH * SEQ * 4)
#define PE_BYTES  ((size_t)SEQ * DIM * 4)

#define TPB_PREP 1024
#define CHUNK    (SEQ / TPB_PREP)                 // 8 tokens / thread
#define PE_BLOCKS ((SEQ * DIM) / (TPB_PREP * 4))  // 1024 (4 floats / thread)

#define NEG_LOG1E4_OVER_256 (-0.03597789207803197f)  // -2*ln(10000)/512
#define INV2PI 0.15915494309189535f
#define SQRT_DIM 22.62741699796952f

// ---------------------------------------------------------------------------
// prep_kernel: blocks [0,BATCH) compute segment ids (two-level monoid scan),
//              blocks [BATCH, BATCH+PE_BLOCKS) fill the pe table.
//
// seg scan per step i (i=1..SEQ-1), carry nc (starts 0):
//   c=t[i]; p=t[i-1];
//   if (36<=c<=41) nc=2;
//   is_note = c<12;
//   flag = is_note ? ((p>=12)||(nc>0)) : (p<12);
//   if (is_note) nc-=1;
// seg = inclusive cumsum of flags (flag for token 0 is 0).
//
// Chunk transform of nc is (reset, val): T(nc) = reset ? val : nc+val, with
// compose(A earlier, B later) = B.reset ? B : (A.reset, A.val+B.val).
// ---------------------------------------------------------------------------
__global__ __launch_bounds__(TPB_PREP)
void prep_kernel(const int* __restrict__ tok, int* __restrict__ seg,
                 float* __restrict__ pe) {
    __shared__ int s_val[TPB_PREP];
    __shared__ int s_rst[TPB_PREP];
    const int tid = threadIdx.x;

    if (blockIdx.x >= BATCH) {
        // ---------------- pe table ----------------
        const int g    = (int)(blockIdx.x - BATCH) * TPB_PREP + tid;
        const int base = g << 2;                  // first of 4 floats
        const float pos = (float)(base >> 9);     // base / DIM
        const int d0   = base & (DIM - 1);        // multiple of 4
        const int k0   = d0 >> 1;

        const float div0 = expf(NEG_LOG1E4_OVER_256 * (float)k0);
        const float div1 = expf(NEG_LOG1E4_OVER_256 * (float)(k0 + 1));

        float r0 = pos * div0 * INV2PI; r0 -= floorf(r0);
        float r1 = pos * div1 * INV2PI; r1 -= floorf(r1);

        float4 o;
        o.x = __builtin_amdgcn_sinf(r0);
        o.y = __builtin_amdgcn_cosf(r0);
        o.z = __builtin_amdgcn_sinf(r1);
        o.w = __builtin_amdgcn_cosf(r1);
        *reinterpret_cast<float4*>(pe + (size_t)base) = o;
        return;
    }

    // ---------------- segment ids ----------------
    const int b  = blockIdx.x;
    const int* t = tok + (size_t)b * SEQ;
    int*      sg = seg + (size_t)b * SEQ;

    const int start = tid * CHUNK;
    const int end   = start + CHUNK;
    const int lo    = (start < 1) ? 1 : start;

    // pass 1: per-chunk nc transform
    int reset = 0, val = 0;
    for (int i = lo; i < end; ++i) {
        int c = t[i];
        if (c >= 36 && c <= 41) { reset = 1; val = 2; }
        if (c < 12) val -= 1;
    }
    s_val[tid] = val;
    s_rst[tid] = reset;
    __syncthreads();

    for (int off = 1; off < TPB_PREP; off <<= 1) {
        int pv = 0, pr = 0;
        if (tid >= off) { pv = s_val[tid - off]; pr = s_rst[tid - off]; }
        __syncthreads();
        if (tid >= off && !s_rst[tid]) {
            s_val[tid] += pv;
            s_rst[tid]  = pr;
        }
        __syncthreads();
    }
    const int nc_entry = (tid == 0) ? 0 : s_val[tid - 1];
    __syncthreads();

    // pass 2: per-chunk flag count with known entry nc
    int nc = nc_entry;
    int total = 0;
    for (int i = lo; i < end; ++i) {
        int c = t[i];
        int p = t[i - 1];
        if (c >= 36 && c <= 41) nc = 2;
        bool is_note = (c < 12);
        int f = is_note ? (int)((p >= 12) || (nc > 0)) : (int)(p < 12);
        if (is_note) nc -= 1;
        total += f;
    }
    s_val[tid] = total;
    __syncthreads();
    for (int off = 1; off < TPB_PREP; off <<= 1) {
        int pv = 0;
        if (tid >= off) pv = s_val[tid - off];
        __syncthreads();
        if (tid >= off) s_val[tid] += pv;
        __syncthreads();
    }
    int run = (tid == 0) ? 0 : s_val[tid - 1];

    // pass 3: recompute flags, write inclusive cumsum
    nc = nc_entry;
    if (start == 0) sg[0] = 0;
    for (int i = lo; i < end; ++i) {
        int c = t[i];
        int p = t[i - 1];
        if (c >= 36 && c <= 41) nc = 2;
        bool is_note = (c < 12);
        int f = is_note ? (int)((p >= 12) || (nc > 0)) : (int)(p < 12);
        if (is_note) nc -= 1;
        run += f;
        sg[i] = run;
    }
}

// ---------------------------------------------------------------------------
// out_kernel: out[row,d] = emb[tok[row],d]*sqrt(512) + pe[seg[row],d]
// One thread = 8 consecutive floats (two float4). 64 threads = one row,
// so tok/seg are wave-uniform; all accesses fully coalesced.
// ---------------------------------------------------------------------------
__global__ __launch_bounds__(256)
void out_kernel(const int*   __restrict__ tok,
                const int*   __restrict__ seg,
                const float* __restrict__ emb,
                const float* __restrict__ pe,
                float*       __restrict__ out) {
    const long long g = (long long)blockIdx.x * 256 + threadIdx.x;
    const int row = (int)(g >> 6);           // 64 threads per row
    const int d0  = ((int)g & 63) << 3;      // 0..504, step 8

    const int token = tok[row];
    const int sg    = seg[row];

    const float4* ep = reinterpret_cast<const float4*>(emb + (size_t)token * DIM + d0);
    const float4* pp = reinterpret_cast<const float4*>(pe  + (size_t)sg    * DIM + d0);
    float4 e0 = ep[0], e1 = ep[1];
    float4 p0 = pp[0], p1 = pp[1];

    float4 o0, o1;
    o0.x = e0.x * SQRT_DIM + p0.x;  o0.y = e0.y * SQRT_DIM + p0.y;
    o0.z = e0.z * SQRT_DIM + p0.z;  o0.w = e0.w * SQRT_DIM + p0.w;
    o1.x = e1.x * SQRT_DIM + p1.x;  o1.y = e1.y * SQRT_DIM + p1.y;
    o1.z = e1.z * SQRT_DIM + p1.z;  o1.w = e1.w * SQRT_DIM + p1.w;

    float4* op = reinterpret_cast<float4*>(out + (size_t)row * DIM + d0);
    op[0] = o0;
    op[1] = o1;
}

// ---------------------------------------------------------------------------
// Fallback (ws too small for the pe table): inline trig per element.
// ---------------------------------------------------------------------------
__global__ __launch_bounds__(256)
void out_kernel_trig(const int*   __restrict__ tok,
                     const int*   __restrict__ seg,
                     const float* __restrict__ emb,
                     float*       __restrict__ out) {
    __shared__ float s_div[256];
    const int tid = threadIdx.x;
    s_div[tid] = expf(NEG_LOG1E4_OVER_256 * 0.5f * (float)(2 * tid));
    __syncthreads();

    const long long g = (long long)blockIdx.x * 256 + tid;
    const int row = (int)(g >> 7);
    const int d0  = ((int)g & 127) << 2;

    const int   token = tok[row];
    const float segf  = (float)seg[row];

    const float4 e = *reinterpret_cast<const float4*>(emb + (size_t)token * DIM + d0);

    const int k0 = d0 >> 1;
    const float div0 = s_div[k0 >> 1 << 1 == k0 ? k0 : k0];  // s_div indexed by pair
    // (s_div[k] holds exp(c*k) for k = 0..255; k0 here is d0/2 which is even-pair idx*?)
    const float dv0 = s_div[k0];
    const float dv1 = s_div[k0 + 1];

    float r0 = segf * dv0 * INV2PI; r0 -= floorf(r0);
    float r1 = segf * dv1 * INV2PI; r1 -= floorf(r1);

    float4 o;
    o.x = e.x * SQRT_DIM + __builtin_amdgcn_sinf(r0);
    o.y = e.y * SQRT_DIM + __builtin_amdgcn_cosf(r0);
    o.z = e.z * SQRT_DIM + __builtin_amdgcn_sinf(r1);
    o.w = e.w * SQRT_DIM + __builtin_amdgcn_cosf(r1);
    *reinterpret_cast<float4*>(out + (size_t)row * DIM + d0) = o;
}

extern "C" void kernel_launch(void* const* d_in, const int* in_sizes, int n_in,
                              void* d_out, int out_size, void* d_ws, size_t ws_size,
                              hipStream_t stream) {
    const int*   tok = (const int*)d_in[0];     // (BATCH, SEQ) int32
    const float* emb = (const float*)d_in[1];   // (VOCAB, DIM) f32
    float*       out = (float*)d_out;           // (BATCH, SEQ, DIM) f32
    int*         seg = (int*)d_ws;
    float*       pe  = (float*)((char*)d_ws + SEG_BYTES);

    const bool have_pe_ws = (ws_size >= SEG_BYTES + PE_BYTES);

    if (have_pe_ws) {
        prep_kernel<<<BATCH + PE_BLOCKS, TPB_PREP, 0, stream>>>(tok, seg, pe);
        const int blocks = (int)((long long)BATCH * SEQ * DIM / 8 / 256);  // 16384
        out_kernel<<<blocks, 256, 0, stream>>>(tok, seg, emb, pe, out);
    } else {
        prep_kernel<<<BATCH, TPB_PREP, 0, stream>>>(tok, seg, pe);
        const int blocks = (int)((long long)BATCH * SEQ * DIM / 4 / 256);  // 32768
        out_kernel_trig<<<blocks, 256, 0, stream>>>(tok, seg, emb, out);
    }
}